// Round 1
// 862.747 us; speedup vs baseline: 1.0779x; 1.0779x over previous
//
#include <hip/hip_runtime.h>
#include <hip/hip_bf16.h>
#include <math.h>

#define NTOT 65536
#define KCB  2048
#define CDIM 256
#define HW   1024

#define OUT_LOSS 16777216
#define OUT_PERP 16777217
#define OUT_ENC  16777218

// bf16 codebook staging lives in the (later overwritten) encodings output region:
#define CBB_OFF_F 33554448   // 1 MB cbb [2048][256] bf16

// workspace byte offsets
#define WS_CK   262144                  // 2048 float
#define WS_IDX  270336                  // 65536 int
#define WS_CNT  532480                  // 2048 int
#define WS_PART 540672                  // 1024 double

#define MARGIN 3e-3f
#define CAP 1024

typedef __attribute__((ext_vector_type(8))) short short8;
typedef __attribute__((ext_vector_type(4))) float f32x4;

// order-preserving float<->uint key (handles negative d~)
__device__ inline unsigned enc_f(float x) {
    unsigned u = __float_as_uint(x);
    return (u & 0x80000000u) ? ~u : (u | 0x80000000u);
}
__device__ inline float dec_f(unsigned e) {
    unsigned u = (e & 0x80000000u) ? (e ^ 0x80000000u) : ~e;
    return __uint_as_float(u);
}

__device__ inline void lds_min_u64(unsigned long long* p, unsigned long long v) {
    unsigned long long old = *p;
    while (v < old) {
        unsigned long long assumed = old;
        old = atomicCAS(p, assumed, v);
        if (old == assumed) break;
    }
}

// codebook prep: cb->bf16 + ||E||^2 (EXACT shuffle-tree order validated round 1) + cntK zero
__global__ __launch_bounds__(256) void k_prep_cb(const float* __restrict__ cb, ushort* __restrict__ cbb,
                                                 float* __restrict__ ck, int* __restrict__ cntK) {
    const int tid = threadIdx.x;
    const int wv = tid >> 6, lane = tid & 63;
    const int r = blockIdx.x * 4 + wv;
    const float* row = cb + (size_t)r * CDIM;
    float4 v = *(const float4*)(row + lane * 4);
    ushort4 o;
    __hip_bfloat16 h;
    h = __float2bfloat16(v.x); o.x = *(ushort*)&h;
    h = __float2bfloat16(v.y); o.y = *(ushort*)&h;
    h = __float2bfloat16(v.z); o.z = *(ushort*)&h;
    h = __float2bfloat16(v.w); o.w = *(ushort*)&h;
    *(ushort4*)(cbb + (size_t)r * CDIM + lane * 4) = o;
    float s = v.x*v.x + v.y*v.y + v.z*v.z + v.w*v.w;
    for (int off = 32; off >= 1; off >>= 1) s += __shfl_down(s, off, 64);
    if (lane == 0) ck[r] = s;
    if (lane == 1) cntK[r] = 0;
}

// ---- FUSED: z-tile stage (LDS, fp32) + bf16 A-frags + srow + MFMA prefilter
//            + exact LDS rescore + gather/out0/loss. One HBM read of z total. ----
// Bitwise invariants preserved vs the validated split kernels:
//  * bf16 inputs: same __float2bfloat16 of the same fp32 values -> identical MFMA/prefilter
//  * srow: identical sequential-fma chain over c=0..255 (values from LDS == global z)
//  * rescore: identical fmaf chain + d = (srow - 2m) + ck, lowest-k tie via u64 pack
//  * gather: identical per-thread (cg,nl) element order, out0 = ze + (q - ze),
//            identical double tree reduction -> part[] bitwise-identical
__global__ __launch_bounds__(256, 2) void k_main(
    const float* __restrict__ z, const float* __restrict__ cb,
    const ushort* __restrict__ cbb, const float* __restrict__ ckg,
    int* __restrict__ indices, int* __restrict__ cntK,
    float* __restrict__ out0, double* __restrict__ part)
{
    // persistent LDS: fp32 z tile zt[c][row], stride 65 (bank-conflict-free)
    __shared__ float ztb[CDIM * 65];                         // 66,560 B
    // phase-overlaid LDS (p1 dead before qc is written; qc dead before sh)
    __shared__ union {
        struct {
            unsigned long long wmin[4][64];                  // 2048 B
            float thrRow[64];                                // 256 B
            float srowL[64];                                 // 256 B
            int   candRK[CAP];                               // 4096 B
        } p1;
        float  qc[32 * 65];                                  // 8320 B (gather staging)
        double sh[256];                                      // 2048 B (loss reduce)
    } u;
    __shared__ unsigned long long best[64];
    __shared__ int cnt;
    __shared__ int allscan;
    // total ~75.4 KB -> 2 blocks/CU (same occupancy as previous k_mfma_argmin)

    const int tid = threadIdx.x;
    const int w = tid >> 6, lane = tid & 63;
    const int col = lane & 15, quad = lane >> 4;
    const int n0 = blockIdx.x * 64;
    const int b = n0 >> 10, hw0 = n0 & 1023;

    // Phase A: stage z tile [256 c][64 rows] fp32, float4-coalesced. Wave w owns c in [w*64, w*64+64).
    {
        const int hwq = tid & 15, csub = (tid >> 4) & 3;
#pragma unroll
        for (int i = 0; i < 16; ++i) {
            const int c = w * 64 + i * 4 + csub;
            float4 v = *(const float4*)(z + ((size_t)b * CDIM + c) * HW + hw0 + hwq * 4);
            float* dst = ztb + c * 65 + hwq * 4;
            dst[0] = v.x; dst[1] = v.y; dst[2] = v.z; dst[3] = v.w;
        }
    }
    if (tid == 0) { cnt = 0; allscan = 0; }
    __syncthreads();

    // Phase B: build A fragments in-register from LDS (identical bf16 to old zb path)
    short8 areg[4][8];
#pragma unroll
    for (int nt = 0; nt < 4; ++nt)
#pragma unroll
        for (int cs = 0; cs < 8; ++cs) {
            short8 a;
#pragma unroll
            for (int j = 0; j < 8; ++j) {
                __hip_bfloat16 h = __float2bfloat16(ztb[(cs * 32 + quad * 8 + j) * 65 + nt * 16 + col]);
                a[j] = *(ushort*)&h;
            }
            areg[nt][cs] = a;
        }

    // wave 0: srow into LDS — EXACT sequential-fma order (same values as global z)
    if (tid < 64) {
        float s = 0.f;
#pragma unroll 8
        for (int c = 0; c < CDIM; ++c) { float v = ztb[c * 65 + tid]; s = fmaf(v, v, s); }
        u.p1.srowL[tid] = s;
    }

    // Phase C: MFMA prefilter with branchless per-thread (m1,k1,m2) tracking (unchanged)
    float m1[16], m2[16]; int k1[16];
#pragma unroll
    for (int s = 0; s < 16; ++s) { m1[s] = INFINITY; m2[s] = INFINITY; k1[s] = 0; }

    for (int k0 = 0; k0 < KCB; k0 += 128) {
        const int kb = k0 + w * 32;
#pragma unroll
        for (int kt = 0; kt < 2; ++kt) {
            const int kk = kb + kt * 16 + col;
            const ushort* bbase = cbb + (size_t)kk * CDIM + quad * 8;
            short8 bfrag[8];
#pragma unroll
            for (int cs = 0; cs < 8; ++cs) bfrag[cs] = *(const short8*)(bbase + cs * 32);
            f32x4 acc[4];
#pragma unroll
            for (int nt = 0; nt < 4; ++nt) acc[nt] = (f32x4){0.f, 0.f, 0.f, 0.f};
#pragma unroll
            for (int cs = 0; cs < 8; ++cs)
#pragma unroll
                for (int nt = 0; nt < 4; ++nt)
                    acc[nt] = __builtin_amdgcn_mfma_f32_16x16x32_bf16(areg[nt][cs], bfrag[cs], acc[nt], 0, 0, 0);
            const float ckv = ckg[kk];
#pragma unroll
            for (int nt = 0; nt < 4; ++nt)
#pragma unroll
                for (int r = 0; r < 4; ++r) {
                    float dt = fmaf(-2.0f, acc[nt][r], ckv);
                    const int s = nt * 4 + r;
                    bool c = dt < m1[s];
                    m2[s] = fminf(m2[s], fmaxf(dt, m1[s]));
                    m1[s] = fminf(m1[s], dt);
                    k1[s] = c ? kk : k1[s];
                }
        }
    }

    // per-row min: butterfly over the 16 col-lanes, then cross-wave via LDS (unchanged)
#pragma unroll
    for (int s = 0; s < 16; ++s) {
        unsigned long long v = ((unsigned long long)enc_f(m1[s]) << 32) | (unsigned)k1[s];
#pragma unroll
        for (int m = 1; m <= 8; m <<= 1) {
            unsigned long long o = __shfl_xor(v, m, 64);
            v = (o < v) ? o : v;
        }
        if (col == 0) u.p1.wmin[w][(s >> 2) * 16 + quad * 4 + (s & 3)] = v;
    }
    if (tid < 64) best[tid] = ~0ull;
    __syncthreads();
    if (tid < 64) {
        unsigned long long v = u.p1.wmin[0][tid];
        unsigned long long o = u.p1.wmin[1][tid]; v = (o < v) ? o : v;
        o = u.p1.wmin[2][tid]; v = (o < v) ? o : v;
        o = u.p1.wmin[3][tid]; v = (o < v) ? o : v;
        u.p1.thrRow[tid] = dec_f((unsigned)(v >> 32)) + MARGIN;
    }
    __syncthreads();

    // push candidates; flagged lanes (m2 within margin) push their whole 32-k subset (unchanged)
#pragma unroll
    for (int s = 0; s < 16; ++s) {
        const int row = (s >> 2) * 16 + quad * 4 + (s & 3);
        const float thr = u.p1.thrRow[row];
        if (m1[s] <= thr) {
            int p = atomicAdd(&cnt, 1);
            if (p < CAP) u.p1.candRK[p] = (row << 16) | k1[s];
        }
        if (m2[s] <= thr) {
            int p = atomicAdd(&cnt, 32);
            if (p + 32 <= CAP) {
#pragma unroll
                for (int k0i = 0; k0i < 16; ++k0i) {
                    int kbase = k0i * 128 + w * 32 + col;
                    u.p1.candRK[p + 2 * k0i]     = (row << 16) | kbase;
                    u.p1.candRK[p + 2 * k0i + 1] = (row << 16) | (kbase + 16);
                }
            }
        }
    }
    __syncthreads();
    if (cnt > CAP) { if (tid == 0) allscan = 1; }
    __syncthreads();
    const int nc = allscan ? 0 : min(cnt, CAP);

    // exact fp32 rescore — identical formula/order, z values now read from LDS
    for (int t = tid; t < nc; t += 256) {
        const int rc = u.p1.candRK[t];
        const int row = rc >> 16, k = rc & 0xFFFF;
        const float* cp = cb + (size_t)k * CDIM;
        float m = 0.f;
#pragma unroll 8
        for (int c = 0; c < CDIM; ++c) m = fmaf(ztb[c * 65 + row], cp[c], m);
        float d = (u.p1.srowL[row] - 2.0f * m) + ckg[k];
        unsigned long long pk = ((unsigned long long)__float_as_uint(d) << 32) | (unsigned)k;
        lds_min_u64(&best[row], pk);
    }
    // overflow fallback (expected never): exact full scan of all rows
    if (allscan) {
        for (int row = 0; row < 64; ++row) {
            const float sr = u.p1.srowL[row];
            for (int kq = 0; kq < 8; ++kq) {
                int k = kq * 256 + tid;
                const float* cp = cb + (size_t)k * CDIM;
                float m = 0.f;
#pragma unroll 8
                for (int c = 0; c < CDIM; ++c) m = fmaf(ztb[c * 65 + row], cp[c], m);
                float d = (sr - 2.0f * m) + ckg[k];
                unsigned long long pk = ((unsigned long long)__float_as_uint(d) << 32) | (unsigned)k;
                lds_min_u64(&best[row], pk);
            }
        }
    }
    __syncthreads();
    if (tid < 64) {
        int bk = (int)(best[tid] & 0xFFFFFFFFull);
        indices[n0 + tid] = bk;
        atomicAdd(&cntK[bk], 1);
    }

    // Phase D: fused gather + out0 + loss. Thread (cg=w, nl=lane) keeps the EXACT
    // element order of the validated k_gather: c = cg*64 + j, j = 0..63 sequential.
    // Staged 32-c chunks through u.qc (p1 is dead; barrier above ordered the overlay).
    const size_t ebase = ((size_t)b * CDIM) * HW + hw0 + lane;
    const int krow = (int)(best[lane] & 0xFFFFFFFFull);   // this thread stages row=lane
    const float* crow = cb + (size_t)krow * CDIM;
    double acc = 0.0;
    for (int q = 0; q < 8; ++q) {
        {   // stage qc[j][row] = cb[k_row][q*32 + j]; wave w supplies j in [w*8, w*8+8)
            float4 v0 = *(const float4*)(crow + q * 32 + w * 8);
            float4 v1 = *(const float4*)(crow + q * 32 + w * 8 + 4);
            float* dst = u.qc + (w * 8) * 65 + lane;
            dst[0 * 65] = v0.x; dst[1 * 65] = v0.y; dst[2 * 65] = v0.z; dst[3 * 65] = v0.w;
            dst[4 * 65] = v1.x; dst[5 * 65] = v1.y; dst[6 * 65] = v1.z; dst[7 * 65] = v1.w;
        }
        __syncthreads();
        if (w == (q >> 1)) {
            const int j0 = (q & 1) * 32;
#pragma unroll 4
            for (int jj = 0; jj < 32; ++jj) {
                const int c = w * 64 + j0 + jj;
                float ze = ztb[c * 65 + lane];
                float qv = u.qc[jj * 65 + lane];
                float d = qv - ze;
                out0[ebase + ((size_t)c << 10)] = ze + d;   // == reference z + (q - z)
                acc += (double)d * (double)d;
            }
        }
        __syncthreads();
    }
    u.sh[tid] = acc;
    __syncthreads();
    for (int s2 = 128; s2 > 0; s2 >>= 1) {
        if (tid < s2) u.sh[tid] += u.sh[tid + s2];
        __syncthreads();
    }
    if (tid == 0) part[blockIdx.x] = u.sh[0];
}

// fused zero + one-hot scatter over [OUT_LOSS, end) as float4 (16B-aligned anchor) — unchanged
__global__ __launch_bounds__(256) void k_encodings(const int* __restrict__ idx, float4* __restrict__ p4,
                                                   float* __restrict__ tail) {
    __shared__ int sidx[17];
    const int tid = threadIdx.x;
    const size_t g0 = (size_t)blockIdx.x * 8192;
    const long f0 = 4L * (long)g0 - 2;
    int nlo = (int)(f0 >> 11); if (nlo < 0) nlo = 0;
    if (tid < 17) { int n = nlo + tid; sidx[tid] = (n < NTOT) ? idx[n] : -1; }
    __syncthreads();
    const float4 zv = make_float4(0.f, 0.f, 0.f, 0.f);
    for (int i = 0; i < 32; ++i) {
        size_t g = g0 + (size_t)i * 256 + tid;
        long fe = 4L * (long)g - 2;
        float4 v = zv;
        if (fe < 0) {
            int kk = sidx[0];
            if (kk == 0) v.z = 1.f;
            if (kk == 1) v.w = 1.f;
        } else {
            int n = (int)(fe >> 11);
            int k0c = (int)(fe & 2047);
            if (k0c >= 2045) {
#pragma unroll
                for (int j = 0; j < 4; ++j) {
                    long fej = fe + j;
                    int nj = (int)(fej >> 11);
                    int kj = (int)(fej & 2047);
                    int li = nj - nlo;
                    int kk = (li >= 0 && li < 17) ? sidx[li] : -2;
                    ((float*)&v)[j] = (kk == kj) ? 1.f : 0.f;
                }
            } else {
                int d = sidx[n - nlo] - k0c;
                if (d >= 0 && d < 4) ((float*)&v)[d] = 1.f;
            }
        }
        p4[g] = v;
    }
    if (blockIdx.x == 0 && tid == 0) {
        int kk = idx[NTOT - 1];
        tail[0] = (kk == 2046) ? 1.f : 0.f;
        tail[1] = (kk == 2047) ? 1.f : 0.f;
    }
}

__global__ __launch_bounds__(256) void k_finalize(const double* __restrict__ part, const int* __restrict__ cnt,
                                                  float* __restrict__ out) {
    __shared__ double sh[256];
    double a = 0.0;
    for (int i = threadIdx.x; i < 1024; i += 256) a += part[i];
    sh[threadIdx.x] = a; __syncthreads();
    for (int s = 128; s > 0; s >>= 1) { if (threadIdx.x < s) sh[threadIdx.x] += sh[threadIdx.x + s]; __syncthreads(); }
    double total = sh[0];
    __syncthreads();
    double p = 0.0;
    for (int i = threadIdx.x; i < 2048; i += 256) {
        double pm = (double)cnt[i] / 65536.0;
        p += pm * log(pm + 1e-10);
    }
    sh[threadIdx.x] = p; __syncthreads();
    for (int s = 128; s > 0; s >>= 1) { if (threadIdx.x < s) sh[threadIdx.x] += sh[threadIdx.x + s]; __syncthreads(); }
    if (threadIdx.x == 0) {
        double mean = total / ((double)NTOT * (double)CDIM);
        out[OUT_LOSS] = (float)(mean * 1.25);
        out[OUT_PERP] = (float)exp(-sh[0]);
    }
}

extern "C" void kernel_launch(void* const* d_in, const int* in_sizes, int n_in,
                              void* d_out, int out_size, void* d_ws, size_t ws_size,
                              hipStream_t stream) {
    const float* z  = (const float*)d_in[0];
    const float* cb = (const float*)d_in[1];
    float* out = (float*)d_out;
    char* ws = (char*)d_ws;
    float*  ck   = (float*)(ws + WS_CK);
    int*    idx  = (int*)(ws + WS_IDX);
    int*    cnt  = (int*)(ws + WS_CNT);
    double* part = (double*)(ws + WS_PART);
    ushort* cbb = (ushort*)(out + CBB_OFF_F);

    hipLaunchKernelGGL(k_prep_cb,   dim3(512),  dim3(256), 0, stream, cb, cbb, ck, cnt);
    hipLaunchKernelGGL(k_main,      dim3(1024), dim3(256), 0, stream, z, cb, cbb, ck, idx, cnt, out, part);
    hipLaunchKernelGGL(k_encodings, dim3(4096), dim3(256), 0, stream, idx, (float4*)(out + OUT_LOSS),
                       out + (OUT_LOSS + (size_t)33554432 * 4));
    hipLaunchKernelGGL(k_finalize,  dim3(1),    dim3(256), 0, stream, part, cnt, out);
}

// Round 2
// 826.399 us; speedup vs baseline: 1.1253x; 1.0440x over previous
//
#include <hip/hip_runtime.h>
#include <hip/hip_bf16.h>
#include <math.h>

#define NTOT 65536
#define KCB  2048
#define CDIM 256
#define HW   1024

#define OUT_LOSS 16777216
#define OUT_PERP 16777217
#define OUT_ENC  16777218

// bf16 codebook staging lives in the encodings output region (cleaned up by k_tail):
#define CBB_OFF_F 33554448   // 64B-aligned; 1 MB cbb [2048][256] bf16
#define CBB_ABS_LO 33554448  // abs float range of cbb region inside out
#define CBB_ABS_HI 34078736  // + 2048*256/2 floats (524288)

// workspace byte offsets
#define WS_CK   262144                  // 2048 float
#define WS_IDX  270336                  // 65536 int
#define WS_CNT  532480                  // 2048 int
#define WS_PART 540672                  // 1024 double

#define MARGIN 3e-3f
#define CAP 1024

typedef __attribute__((ext_vector_type(8))) short short8;
typedef __attribute__((ext_vector_type(4))) float f32x4;

// order-preserving float<->uint key (handles negative d~)
__device__ inline unsigned enc_f(float x) {
    unsigned u = __float_as_uint(x);
    return (u & 0x80000000u) ? ~u : (u | 0x80000000u);
}
__device__ inline float dec_f(unsigned e) {
    unsigned u = (e & 0x80000000u) ? (e ^ 0x80000000u) : ~e;
    return __uint_as_float(u);
}

__device__ inline void lds_min_u64(unsigned long long* p, unsigned long long v) {
    unsigned long long old = *p;
    while (v < old) {
        unsigned long long assumed = old;
        old = atomicCAS(p, assumed, v);
        if (old == assumed) break;
    }
}

// codebook prep: cb->bf16 + ||E||^2 (EXACT shuffle-tree order validated round 1) + cntK zero
__global__ __launch_bounds__(256) void k_prep_cb(const float* __restrict__ cb, ushort* __restrict__ cbb,
                                                 float* __restrict__ ck, int* __restrict__ cntK) {
    const int tid = threadIdx.x;
    const int wv = tid >> 6, lane = tid & 63;
    const int r = blockIdx.x * 4 + wv;
    const float* row = cb + (size_t)r * CDIM;
    float4 v = *(const float4*)(row + lane * 4);
    ushort4 o;
    __hip_bfloat16 h;
    h = __float2bfloat16(v.x); o.x = *(ushort*)&h;
    h = __float2bfloat16(v.y); o.y = *(ushort*)&h;
    h = __float2bfloat16(v.z); o.z = *(ushort*)&h;
    h = __float2bfloat16(v.w); o.w = *(ushort*)&h;
    *(ushort4*)(cbb + (size_t)r * CDIM + lane * 4) = o;
    float s = v.x*v.x + v.y*v.y + v.z*v.z + v.w*v.w;
    for (int off = 32; off >= 1; off >>= 1) s += __shfl_down(s, off, 64);
    if (lane == 0) ck[r] = s;
    if (lane == 1) cntK[r] = 0;
}

// ---- FUSED: z-tile stage (LDS) + srow + MFMA prefilter + exact LDS rescore
//            + gather/out0/loss + PER-BLOCK ENCODINGS SLAB (zero-fill interleaved
//            with the MFMA loop; one-hot scatter after argmin). ----
// Block owns encodings rows n0..n0+63: abs floats [OUT_ENC+n0*2048, +131072).
// Slab starts 8B-aligned (OUT_ENC%4==2): head float2, 32767 float4, tail float2.
// Stores into the live cbb region [CBB_ABS_LO,CBB_ABS_HI) are SKIPPED (written by
// k_tail after k_main completes) -- cbb is concurrently read by other blocks.
// Float4 grid (≡2 mod 4) never straddles the region bounds (also ≡2 mod 4).
// WAW ordering zero->one: __syncthreads() drains vmcnt(0) before s_barrier.
__global__ __launch_bounds__(256, 2) void k_main(
    const float* __restrict__ z, const float* __restrict__ cb,
    const ushort* __restrict__ cbb, const float* __restrict__ ckg,
    int* __restrict__ indices, int* __restrict__ cntK,
    float* __restrict__ out0, double* __restrict__ part)
{
    // persistent LDS: fp32 z tile zt[c][row], stride 65 (bank-conflict-free)
    __shared__ float ztb[CDIM * 65];                         // 66,560 B
    // phase-overlaid LDS (p1 dead before qc is written; qc dead before sh)
    __shared__ union {
        struct {
            unsigned long long wmin[4][64];                  // 2048 B
            float thrRow[64];                                // 256 B
            float srowL[64];                                 // 256 B
            int   candRK[CAP];                               // 4096 B
        } p1;
        float  qc[32 * 65];                                  // 8320 B (gather staging)
        double sh[256];                                      // 2048 B (loss reduce)
    } u;
    __shared__ unsigned long long best[64];
    __shared__ int cnt;
    __shared__ int allscan;

    const int tid = threadIdx.x;
    const int w = tid >> 6, lane = tid & 63;
    const int col = lane & 15, quad = lane >> 4;
    const int n0 = blockIdx.x * 64;
    const int b = n0 >> 10, hw0 = n0 & 1023;

    // encodings slab geometry (abs float indices into out0)
    const int SB = OUT_ENC + n0 * 2048;          // slab head (float2, ≡2 mod 4)
    const int slabF4 = SB + 2;                   // first float4 (16B-aligned)
    const float4 zero4 = make_float4(0.f, 0.f, 0.f, 0.f);

    // Phase A: stage z tile [256 c][64 rows] fp32, float4-coalesced. Wave w owns c in [w*64, w*64+64).
    {
        const int hwq = tid & 15, csub = (tid >> 4) & 3;
#pragma unroll
        for (int i = 0; i < 16; ++i) {
            const int c = w * 64 + i * 4 + csub;
            float4 v = *(const float4*)(z + ((size_t)b * CDIM + c) * HW + hw0 + hwq * 4);
            float* dst = ztb + c * 65 + hwq * 4;
            dst[0] = v.x; dst[1] = v.y; dst[2] = v.z; dst[3] = v.w;
        }
    }
    // slab head/tail float2 (skip if inside live cbb region)
    if (tid == 0) {
        if (!(SB >= CBB_ABS_LO && SB < CBB_ABS_HI)) *(float2*)(out0 + SB) = make_float2(0.f, 0.f);
    }
    if (tid == 1) {
        const int Ft = SB + 131070;
        if (!(Ft >= CBB_ABS_LO && Ft < CBB_ABS_HI)) *(float2*)(out0 + Ft) = make_float2(0.f, 0.f);
    }
    if (tid == 0) { cnt = 0; allscan = 0; }
    __syncthreads();

    // Phase B: build A fragments in-register from LDS (identical bf16 to validated path)
    short8 areg[4][8];
#pragma unroll
    for (int nt = 0; nt < 4; ++nt)
#pragma unroll
        for (int cs = 0; cs < 8; ++cs) {
            short8 a;
#pragma unroll
            for (int j = 0; j < 8; ++j) {
                __hip_bfloat16 h = __float2bfloat16(ztb[(cs * 32 + quad * 8 + j) * 65 + nt * 16 + col]);
                a[j] = *(ushort*)&h;
            }
            areg[nt][cs] = a;
        }

    // wave 0: srow into LDS — EXACT sequential-fma order (same values as global z)
    if (tid < 64) {
        float s = 0.f;
#pragma unroll 8
        for (int c = 0; c < CDIM; ++c) { float v = ztb[c * 65 + tid]; s = fmaf(v, v, s); }
        u.p1.srowL[tid] = s;
    }

    // Phase C: MFMA prefilter with branchless per-thread (m1,k1,m2) tracking.
    // Interleaved: 8 float4 zero-stores of the encodings slab per K-step
    // (128 B/lane/step drains well under the step's ~700 cy; no vmcnt stall).
    float m1[16], m2[16]; int k1[16];
#pragma unroll
    for (int s = 0; s < 16; ++s) { m1[s] = INFINITY; m2[s] = INFINITY; k1[s] = 0; }

    for (int k0 = 0; k0 < KCB; k0 += 128) {
        {
            const int it0 = (k0 >> 7) * 8;
#pragma unroll
            for (int ii = 0; ii < 8; ++ii) {
                const int j = (it0 + ii) * 256 + tid;     // 0..32767; 32767 is the overhang -> skip
                const int F = slabF4 + 4 * j;
                if (j < 32767 && !(F >= CBB_ABS_LO && F < CBB_ABS_HI))
                    *(float4*)(out0 + F) = zero4;
            }
        }
        const int kb = k0 + w * 32;
#pragma unroll
        for (int kt = 0; kt < 2; ++kt) {
            const int kk = kb + kt * 16 + col;
            const ushort* bbase = cbb + (size_t)kk * CDIM + quad * 8;
            short8 bfrag[8];
#pragma unroll
            for (int cs = 0; cs < 8; ++cs) bfrag[cs] = *(const short8*)(bbase + cs * 32);
            f32x4 acc[4];
#pragma unroll
            for (int nt = 0; nt < 4; ++nt) acc[nt] = (f32x4){0.f, 0.f, 0.f, 0.f};
#pragma unroll
            for (int cs = 0; cs < 8; ++cs)
#pragma unroll
                for (int nt = 0; nt < 4; ++nt)
                    acc[nt] = __builtin_amdgcn_mfma_f32_16x16x32_bf16(areg[nt][cs], bfrag[cs], acc[nt], 0, 0, 0);
            const float ckv = ckg[kk];
#pragma unroll
            for (int nt = 0; nt < 4; ++nt)
#pragma unroll
                for (int r = 0; r < 4; ++r) {
                    float dt = fmaf(-2.0f, acc[nt][r], ckv);
                    const int s = nt * 4 + r;
                    bool c = dt < m1[s];
                    m2[s] = fminf(m2[s], fmaxf(dt, m1[s]));
                    m1[s] = fminf(m1[s], dt);
                    k1[s] = c ? kk : k1[s];
                }
        }
    }

    // per-row min: butterfly over the 16 col-lanes, then cross-wave via LDS (unchanged)
#pragma unroll
    for (int s = 0; s < 16; ++s) {
        unsigned long long v = ((unsigned long long)enc_f(m1[s]) << 32) | (unsigned)k1[s];
#pragma unroll
        for (int m = 1; m <= 8; m <<= 1) {
            unsigned long long o = __shfl_xor(v, m, 64);
            v = (o < v) ? o : v;
        }
        if (col == 0) u.p1.wmin[w][(s >> 2) * 16 + quad * 4 + (s & 3)] = v;
    }
    if (tid < 64) best[tid] = ~0ull;
    __syncthreads();
    if (tid < 64) {
        unsigned long long v = u.p1.wmin[0][tid];
        unsigned long long o = u.p1.wmin[1][tid]; v = (o < v) ? o : v;
        o = u.p1.wmin[2][tid]; v = (o < v) ? o : v;
        o = u.p1.wmin[3][tid]; v = (o < v) ? o : v;
        u.p1.thrRow[tid] = dec_f((unsigned)(v >> 32)) + MARGIN;
    }
    __syncthreads();

    // push candidates; flagged lanes (m2 within margin) push their whole 32-k subset (unchanged)
#pragma unroll
    for (int s = 0; s < 16; ++s) {
        const int row = (s >> 2) * 16 + quad * 4 + (s & 3);
        const float thr = u.p1.thrRow[row];
        if (m1[s] <= thr) {
            int p = atomicAdd(&cnt, 1);
            if (p < CAP) u.p1.candRK[p] = (row << 16) | k1[s];
        }
        if (m2[s] <= thr) {
            int p = atomicAdd(&cnt, 32);
            if (p + 32 <= CAP) {
#pragma unroll
                for (int k0i = 0; k0i < 16; ++k0i) {
                    int kbase = k0i * 128 + w * 32 + col;
                    u.p1.candRK[p + 2 * k0i]     = (row << 16) | kbase;
                    u.p1.candRK[p + 2 * k0i + 1] = (row << 16) | (kbase + 16);
                }
            }
        }
    }
    __syncthreads();
    if (cnt > CAP) { if (tid == 0) allscan = 1; }
    __syncthreads();
    const int nc = allscan ? 0 : min(cnt, CAP);

    // exact fp32 rescore — identical formula/order, z values from LDS
    for (int t = tid; t < nc; t += 256) {
        const int rc = u.p1.candRK[t];
        const int row = rc >> 16, k = rc & 0xFFFF;
        const float* cp = cb + (size_t)k * CDIM;
        float m = 0.f;
#pragma unroll 8
        for (int c = 0; c < CDIM; ++c) m = fmaf(ztb[c * 65 + row], cp[c], m);
        float d = (u.p1.srowL[row] - 2.0f * m) + ckg[k];
        unsigned long long pk = ((unsigned long long)__float_as_uint(d) << 32) | (unsigned)k;
        lds_min_u64(&best[row], pk);
    }
    // overflow fallback (expected never): exact full scan of all rows
    if (allscan) {
        for (int row = 0; row < 64; ++row) {
            const float sr = u.p1.srowL[row];
            for (int kq = 0; kq < 8; ++kq) {
                int k = kq * 256 + tid;
                const float* cp = cb + (size_t)k * CDIM;
                float m = 0.f;
#pragma unroll 8
                for (int c = 0; c < CDIM; ++c) m = fmaf(ztb[c * 65 + row], cp[c], m);
                float d = (sr - 2.0f * m) + ckg[k];
                unsigned long long pk = ((unsigned long long)__float_as_uint(d) << 32) | (unsigned)k;
                lds_min_u64(&best[row], pk);
            }
        }
    }
    __syncthreads();   // drains vmcnt(0): all zero stores at coherence point before the 1.0 stores
    if (tid < 64) {
        int bk = (int)(best[tid] & 0xFFFFFFFFull);
        indices[n0 + tid] = bk;
        atomicAdd(&cntK[bk], 1);
        const int F1 = OUT_ENC + (n0 + tid) * 2048 + bk;   // one-hot scatter
        if (!(F1 >= CBB_ABS_LO && F1 < CBB_ABS_HI)) out0[F1] = 1.0f;
    }

    // Phase D: fused gather + out0 + loss (unchanged; bitwise-identical order)
    const size_t ebase = ((size_t)b * CDIM) * HW + hw0 + lane;
    const int krow = (int)(best[lane] & 0xFFFFFFFFull);
    const float* crow = cb + (size_t)krow * CDIM;
    double acc = 0.0;
    for (int q = 0; q < 8; ++q) {
        {
            float4 v0 = *(const float4*)(crow + q * 32 + w * 8);
            float4 v1 = *(const float4*)(crow + q * 32 + w * 8 + 4);
            float* dst = u.qc + (w * 8) * 65 + lane;
            dst[0 * 65] = v0.x; dst[1 * 65] = v0.y; dst[2 * 65] = v0.z; dst[3 * 65] = v0.w;
            dst[4 * 65] = v1.x; dst[5 * 65] = v1.y; dst[6 * 65] = v1.z; dst[7 * 65] = v1.w;
        }
        __syncthreads();
        if (w == (q >> 1)) {
            const int j0 = (q & 1) * 32;
#pragma unroll 4
            for (int jj = 0; jj < 32; ++jj) {
                const int c = w * 64 + j0 + jj;
                float ze = ztb[c * 65 + lane];
                float qv = u.qc[jj * 65 + lane];
                float d = qv - ze;
                out0[ebase + ((size_t)c << 10)] = ze + d;
                acc += (double)d * (double)d;
            }
        }
        __syncthreads();
    }
    u.sh[tid] = acc;
    __syncthreads();
    for (int s2 = 128; s2 > 0; s2 >>= 1) {
        if (tid < s2) u.sh[tid] += u.sh[tid + s2];
        __syncthreads();
    }
    if (tid == 0) part[blockIdx.x] = u.sh[0];
}

// cleanup (blocks 0..511): rewrite the cbb-staging 2 MB of the encodings region
// from idx (zero + one-hot), now that k_main no longer reads cbb.
// finalize (block 512): loss/perplexity reduction (unchanged math).
__global__ __launch_bounds__(256) void k_tail(const int* __restrict__ idx, const double* __restrict__ part,
                                              const int* __restrict__ cnt, float* __restrict__ out) {
    if (blockIdx.x < 512) {
        const int t = blockIdx.x * 256 + threadIdx.x;   // 0..131071 float4s
        const int F = CBB_ABS_LO + 4 * t;               // 16B-aligned (CBB_ABS_LO % 4 == 0)
        const int rel = F - OUT_ENC;                    // enc-relative float index
        float4 v;
#pragma unroll
        for (int j = 0; j < 4; ++j) {
            const int fr = rel + j;
            const int n = fr >> 11, k = fr & 2047;
            ((float*)&v)[j] = (idx[n] == k) ? 1.f : 0.f;
        }
        *(float4*)(out + F) = v;
        return;
    }
    __shared__ double sh[256];
    double a = 0.0;
    for (int i = threadIdx.x; i < 1024; i += 256) a += part[i];
    sh[threadIdx.x] = a; __syncthreads();
    for (int s = 128; s > 0; s >>= 1) { if (threadIdx.x < s) sh[threadIdx.x] += sh[threadIdx.x + s]; __syncthreads(); }
    double total = sh[0];
    __syncthreads();
    double p = 0.0;
    for (int i = threadIdx.x; i < 2048; i += 256) {
        double pm = (double)cnt[i] / 65536.0;
        p += pm * log(pm + 1e-10);
    }
    sh[threadIdx.x] = p; __syncthreads();
    for (int s = 128; s > 0; s >>= 1) { if (threadIdx.x < s) sh[threadIdx.x] += sh[threadIdx.x + s]; __syncthreads(); }
    if (threadIdx.x == 0) {
        double mean = total / ((double)NTOT * (double)CDIM);
        out[OUT_LOSS] = (float)(mean * 1.25);
        out[OUT_PERP] = (float)exp(-sh[0]);
    }
}

extern "C" void kernel_launch(void* const* d_in, const int* in_sizes, int n_in,
                              void* d_out, int out_size, void* d_ws, size_t ws_size,
                              hipStream_t stream) {
    const float* z  = (const float*)d_in[0];
    const float* cb = (const float*)d_in[1];
    float* out = (float*)d_out;
    char* ws = (char*)d_ws;
    float*  ck   = (float*)(ws + WS_CK);
    int*    idx  = (int*)(ws + WS_IDX);
    int*    cnt  = (int*)(ws + WS_CNT);
    double* part = (double*)(ws + WS_PART);
    ushort* cbb = (ushort*)(out + CBB_OFF_F);

    hipLaunchKernelGGL(k_prep_cb, dim3(512),  dim3(256), 0, stream, cb, cbb, ck, cnt);
    hipLaunchKernelGGL(k_main,    dim3(1024), dim3(256), 0, stream, z, cb, cbb, ck, idx, cnt, out, part);
    hipLaunchKernelGGL(k_tail,    dim3(513),  dim3(256), 0, stream, idx, part, cnt, out);
}